// Round 1
// baseline (535.465 us; speedup 1.0000x reference)
//
#include <hip/hip_runtime.h>

#define NN 50000
#define NE 800000

constexpr int H1 = 4, C1 = 64, F1 = 128, HC1 = 256;
constexpr int HC2 = 128;

// ---------------- edge index access (int32 vs int64 hedge) ----------------
__device__ __forceinline__ int ld_edge(const int* e32, const long long* e64, int is64, long long idx) {
    return is64 ? (int)e64[idx] : e32[idx];
}

__global__ void k_detect(const int* __restrict__ e32, int* __restrict__ flag) {
    if (threadIdx.x == 0 && blockIdx.x == 0) {
        int z = 1;
        for (int i = 0; i < 16; i++)
            if (e32[2 * i + 1] != 0) z = 0;   // int64 little-endian high words
        *flag = z;
    }
}

// ---------------- CSR build ----------------
__global__ void k_zero(int* __restrict__ p, int n) {
    int i = blockIdx.x * blockDim.x + threadIdx.x;
    if (i < n) p[i] = 0;
}

__global__ void k_count(const int* __restrict__ e32, const long long* __restrict__ e64,
                        const int* __restrict__ flag, int* __restrict__ deg) {
    int e = blockIdx.x * blockDim.x + threadIdx.x;
    if (e >= NE) return;
    int is64 = *flag;
    int dst = ld_edge(e32, e64, is64, (long long)NE + e);
    atomicAdd(&deg[dst], 1);
}

__global__ void k_scan(const int* __restrict__ deg, int* __restrict__ row_ptr) {
    __shared__ int wsum[16];
    __shared__ int carry_s;
    const int tid = threadIdx.x;
    const int lane = tid & 63, wv = tid >> 6;
    if (tid == 0) carry_s = 0;
    __syncthreads();
    for (int base = 0; base < NN; base += 1024) {
        int i = base + tid;
        int v = (i < NN) ? deg[i] : 0;
        int x = v;
        #pragma unroll
        for (int off = 1; off < 64; off <<= 1) {
            int t = __shfl_up(x, off);
            if (lane >= off) x += t;
        }
        if (lane == 63) wsum[wv] = x;
        __syncthreads();
        if (tid == 0) {
            int run = carry_s;
            #pragma unroll
            for (int j = 0; j < 16; j++) { int t = wsum[j]; wsum[j] = run; run += t; }
            carry_s = run;
        }
        __syncthreads();
        int excl = x - v + wsum[wv];
        if (i < NN) row_ptr[i] = excl;
        __syncthreads();
    }
    if (tid == 0) row_ptr[NN] = carry_s;
}

__global__ void k_initcur(const int* __restrict__ row_ptr, int* __restrict__ cursor) {
    int i = blockIdx.x * blockDim.x + threadIdx.x;
    if (i < NN) cursor[i] = row_ptr[i];
}

__global__ void k_fill(const int* __restrict__ e32, const long long* __restrict__ e64,
                       const int* __restrict__ flag, int* __restrict__ cursor, int* __restrict__ col) {
    int e = blockIdx.x * blockDim.x + threadIdx.x;
    if (e >= NE) return;
    int is64 = *flag;
    int src = ld_edge(e32, e64, is64, e);
    int dst = ld_edge(e32, e64, is64, (long long)NE + e);
    int pos = atomicAdd(&cursor[dst], 1);
    col[pos] = src;
}

// ---------------- fused GEMM + attention-logit epilogue ----------------
// A[M,K] @ W[K,NOUT] -> Hout[M,NOUT]; also as_out[M,HEADS], ad_out[M,HEADS]
template <int K, int NOUT, int HEADS>
__global__ __launch_bounds__(256) void k_gemm_att(
    const float* __restrict__ A, const float* __restrict__ W,
    const float* __restrict__ atts, const float* __restrict__ attd,
    float* __restrict__ Hout, float* __restrict__ as_out, float* __restrict__ ad_out, int M)
{
    constexpr int BM = 64, BK = 32;
    constexpr int TN = NOUT / 16;
    constexpr int C = NOUT / HEADS;
    __shared__ float As[BM][BK + 4];
    __shared__ float Bs[BK][NOUT];
    __shared__ float red_s[BM * HEADS];
    __shared__ float red_d[BM * HEADS];
    const int tid = threadIdx.x;
    const int tc = tid & 15, tr = tid >> 4;
    const int row0 = blockIdx.x * BM;

    float acc[4][TN];
    #pragma unroll
    for (int r = 0; r < 4; r++)
        #pragma unroll
        for (int j = 0; j < TN; j++) acc[r][j] = 0.f;

    for (int kc = 0; kc < K; kc += BK) {
        // A tile: 64x32 floats = 512 float4, 2 per thread
        #pragma unroll
        for (int j = 0; j < 2; j++) {
            int idx = tid + j * 256;
            int r = idx >> 3, c4 = (idx & 7) * 4;
            float4 v = make_float4(0.f, 0.f, 0.f, 0.f);
            int gr = row0 + r;
            if (gr < M) v = *(const float4*)(A + (size_t)gr * K + kc + c4);
            *(float4*)&As[r][c4] = v;
        }
        // B tile: BK x NOUT
        #pragma unroll
        for (int j = 0; j < BK * NOUT / 4 / 256; j++) {
            int idx = tid + j * 256;
            int r = idx / (NOUT / 4), c4 = (idx % (NOUT / 4)) * 4;
            *(float4*)&Bs[r][c4] = *(const float4*)(W + (size_t)(kc + r) * NOUT + c4);
        }
        __syncthreads();
        #pragma unroll
        for (int k = 0; k < BK; k++) {
            float a[4];
            #pragma unroll
            for (int r = 0; r < 4; r++) a[r] = As[tr * 4 + r][k];
            float b[TN];
            #pragma unroll
            for (int j = 0; j < TN; j += 4) *(float4*)&b[j] = *(const float4*)&Bs[k][tc * TN + j];
            #pragma unroll
            for (int r = 0; r < 4; r++)
                #pragma unroll
                for (int j = 0; j < TN; j++) acc[r][j] = fmaf(a[r], b[j], acc[r][j]);
        }
        __syncthreads();
    }

    // write projected features
    #pragma unroll
    for (int r = 0; r < 4; r++) {
        int gr = row0 + tr * 4 + r;
        if (gr < M) {
            #pragma unroll
            for (int j = 0; j < TN; j += 4)
                *(float4*)(Hout + (size_t)gr * NOUT + tc * TN + j) = *(float4*)&acc[r][j];
        }
    }

    // attention logit partial dots -> LDS reduce
    for (int idx = tid; idx < BM * HEADS; idx += 256) { red_s[idx] = 0.f; red_d[idx] = 0.f; }
    __syncthreads();
    const int col0 = tc * TN;
    const int head = col0 / C;   // TN divides C, so single head per thread
    #pragma unroll
    for (int r = 0; r < 4; r++) {
        float ps = 0.f, pd = 0.f;
        #pragma unroll
        for (int j = 0; j < TN; j++) {
            ps = fmaf(acc[r][j], atts[col0 + j], ps);
            pd = fmaf(acc[r][j], attd[col0 + j], pd);
        }
        atomicAdd(&red_s[(tr * 4 + r) * HEADS + head], ps);
        atomicAdd(&red_d[(tr * 4 + r) * HEADS + head], pd);
    }
    __syncthreads();
    for (int idx = tid; idx < BM * HEADS; idx += 256) {
        int r = idx / HEADS;
        int gr = row0 + r;
        if (gr < M) {
            as_out[(size_t)gr * HEADS + (idx % HEADS)] = red_s[idx];
            ad_out[(size_t)gr * HEADS + (idx % HEADS)] = red_d[idx];
        }
    }
}

// ---------------- aggregation layer 1: wave per dst node, online softmax ----------------
__global__ __launch_bounds__(256) void k_agg1(
    const int* __restrict__ row_ptr, const int* __restrict__ col,
    const float* __restrict__ Hp, const float* __restrict__ as_, const float* __restrict__ ad_,
    const float* __restrict__ bias, float* __restrict__ outp)
{
    int n = blockIdx.x * 4 + (threadIdx.x >> 6);
    if (n >= NN) return;
    int lane = threadIdx.x & 63;
    int head = lane >> 4;            // cols lane*4 .. lane*4+3 all in head lane/16
    float ad0 = ad_[(size_t)n * H1 + head];
    int beg = row_ptr[n], end = row_ptr[n + 1];
    float m = -1e30f, s = 0.f;
    float4 acc = make_float4(0.f, 0.f, 0.f, 0.f);
    for (int e = beg - 1; e < end; ++e) {
        int src = (e < beg) ? n : col[e];
        float ev = as_[(size_t)src * H1 + head] + ad0;
        ev = ev > 0.f ? ev : 0.2f * ev;                 // leaky_relu
        float nm = fmaxf(m, ev);
        float sc = __expf(m - nm);
        float p  = __expf(ev - nm);
        s = s * sc + p;
        m = nm;
        float4 hv = *(const float4*)(Hp + (size_t)src * HC1 + lane * 4);
        acc.x = acc.x * sc + p * hv.x;
        acc.y = acc.y * sc + p * hv.y;
        acc.z = acc.z * sc + p * hv.z;
        acc.w = acc.w * sc + p * hv.w;
    }
    float inv = 1.f / s;
    float4 bv = *(const float4*)(bias + lane * 4);
    float4 o;
    o.x = acc.x * inv + bv.x;
    o.y = acc.y * inv + bv.y;
    o.z = acc.z * inv + bv.z;
    o.w = acc.w * inv + bv.w;
    // ELU between layers
    o.x = o.x > 0.f ? o.x : __expf(o.x) - 1.f;
    o.y = o.y > 0.f ? o.y : __expf(o.y) - 1.f;
    o.z = o.z > 0.f ? o.z : __expf(o.z) - 1.f;
    o.w = o.w > 0.f ? o.w : __expf(o.w) - 1.f;
    *(float4*)(outp + (size_t)n * HC1 + lane * 4) = o;
}

// ---------------- aggregation layer 2 (single head, final output) ----------------
__global__ __launch_bounds__(256) void k_agg2(
    const int* __restrict__ row_ptr, const int* __restrict__ col,
    const float* __restrict__ Hp, const float* __restrict__ as_, const float* __restrict__ ad_,
    const float* __restrict__ bias, float* __restrict__ outp)
{
    int n = blockIdx.x * 4 + (threadIdx.x >> 6);
    if (n >= NN) return;
    int lane = threadIdx.x & 63;
    float ad0 = ad_[n];
    int beg = row_ptr[n], end = row_ptr[n + 1];
    float m = -1e30f, s = 0.f;
    float2 acc = make_float2(0.f, 0.f);
    for (int e = beg - 1; e < end; ++e) {
        int src = (e < beg) ? n : col[e];
        float ev = as_[src] + ad0;
        ev = ev > 0.f ? ev : 0.2f * ev;
        float nm = fmaxf(m, ev);
        float sc = __expf(m - nm);
        float p  = __expf(ev - nm);
        s = s * sc + p;
        m = nm;
        float2 hv = *(const float2*)(Hp + (size_t)src * HC2 + lane * 2);
        acc.x = acc.x * sc + p * hv.x;
        acc.y = acc.y * sc + p * hv.y;
    }
    float inv = 1.f / s;
    float2 bv = *(const float2*)(bias + lane * 2);
    float2 o = make_float2(acc.x * inv + bv.x, acc.y * inv + bv.y);
    *(float2*)(outp + (size_t)n * HC2 + lane * 2) = o;
}

// ---------------- launch ----------------
extern "C" void kernel_launch(void* const* d_in, const int* in_sizes, int n_in,
                              void* d_out, int out_size, void* d_ws, size_t ws_size,
                              hipStream_t stream) {
    const float* x   = (const float*)d_in[0];
    const int*       e32 = (const int*)d_in[1];
    const long long* e64 = (const long long*)d_in[1];
    const float* W1  = (const float*)d_in[2];
    const float* as1w = (const float*)d_in[3];
    const float* ad1w = (const float*)d_in[4];
    const float* b1  = (const float*)d_in[5];
    const float* W2  = (const float*)d_in[6];
    const float* as2w = (const float*)d_in[7];
    const float* ad2w = (const float*)d_in[8];
    const float* b2  = (const float*)d_in[9];
    float* out = (float*)d_out;

    char* w = (char*)d_ws;
    auto carve = [&](size_t bytes) -> void* {
        void* p = (void*)w;
        w += (bytes + 255) & ~(size_t)255;
        return p;
    };
    int*   flag    = (int*)carve(4);
    int*   row_ptr = (int*)carve((NN + 1) * sizeof(int));
    int*   cursor  = (int*)carve(NN * sizeof(int));
    int*   col     = (int*)carve(NE * sizeof(int));
    float* as1     = (float*)carve((size_t)NN * H1 * sizeof(float));
    float* ad1     = (float*)carve((size_t)NN * H1 * sizeof(float));
    float* as2     = (float*)carve((size_t)NN * sizeof(float));
    float* ad2     = (float*)carve((size_t)NN * sizeof(float));
    float* h1      = (float*)carve((size_t)NN * HC1 * sizeof(float));   // also reused for h2 proj
    float* h2in    = (float*)carve((size_t)NN * HC1 * sizeof(float));
    float* h2      = h1;  // h1 dead once agg1 finished; gemm2 reuses the buffer

    const int TPB = 256;
    const int gN  = (NN + TPB - 1) / TPB;
    const int gE  = (NE + TPB - 1) / TPB;
    const int gM  = (NN + 63) / 64;
    const int gAgg = (NN + 3) / 4;

    // CSR build
    k_detect<<<1, 64, 0, stream>>>(e32, flag);
    k_zero<<<gN, TPB, 0, stream>>>(cursor, NN);
    k_count<<<gE, TPB, 0, stream>>>(e32, e64, flag, cursor);
    k_scan<<<1, 1024, 0, stream>>>(cursor, row_ptr);
    k_initcur<<<gN, TPB, 0, stream>>>(row_ptr, cursor);
    k_fill<<<gE, TPB, 0, stream>>>(e32, e64, flag, cursor, col);

    // layer 1
    k_gemm_att<F1, HC1, H1><<<gM, TPB, 0, stream>>>(x, W1, as1w, ad1w, h1, as1, ad1, NN);
    k_agg1<<<gAgg, TPB, 0, stream>>>(row_ptr, col, h1, as1, ad1, b1, h2in);

    // layer 2
    k_gemm_att<HC1, HC2, 1><<<gM, TPB, 0, stream>>>(h2in, W2, as2w, ad2w, h2, as2, ad2, NN);
    k_agg2<<<gAgg, TPB, 0, stream>>>(row_ptr, col, h2, as2, ad2, b2, out);
}

// Round 3
// 458.637 us; speedup vs baseline: 1.1675x; 1.1675x over previous
//
#include <hip/hip_runtime.h>
#include <hip/hip_bf16.h>

#define NN 50000
#define NE 800000

constexpr int H1 = 4, C1 = 64, F1 = 128, HC1 = 256;
constexpr int HC2 = 128;

typedef unsigned short u16;
typedef unsigned int u32;

__device__ __forceinline__ float bf2f(u16 h) {
    return __uint_as_float(((u32)h) << 16);
}
__device__ __forceinline__ u16 f2bf(float f) {
    u32 u = __float_as_uint(f);
    u32 r = (u + 0x7fffu + ((u >> 16) & 1u)) >> 16;   // RTN-even
    return (u16)r;
}

// ---------------- edge index access (int32 vs int64 hedge) ----------------
__device__ __forceinline__ int ld_edge(const int* e32, const long long* e64, int is64, long long idx) {
    return is64 ? (int)e64[idx] : e32[idx];
}

__global__ void k_detect(const int* __restrict__ e32, int* __restrict__ flag) {
    if (threadIdx.x == 0 && blockIdx.x == 0) {
        int z = 1;
        for (int i = 0; i < 16; i++)
            if (e32[2 * i + 1] != 0) z = 0;   // int64 little-endian high words
        *flag = z;
    }
}

// ---------------- CSR build ----------------
__global__ void k_zero(int* __restrict__ p, int n) {
    int i = blockIdx.x * blockDim.x + threadIdx.x;
    if (i < n) p[i] = 0;
}

__global__ void k_count(const int* __restrict__ e32, const long long* __restrict__ e64,
                        const int* __restrict__ flag, int* __restrict__ deg) {
    int e = blockIdx.x * blockDim.x + threadIdx.x;
    if (e >= NE) return;
    int is64 = *flag;
    int dst = ld_edge(e32, e64, is64, (long long)NE + e);
    atomicAdd(&deg[dst], 1);
}

// work-efficient single-block scan: 1024 threads x 49 contiguous elems each
__global__ __launch_bounds__(1024) void k_scan(const int* __restrict__ deg, int* __restrict__ row_ptr) {
    constexpr int CH = 49;   // 1024*49 = 50176 >= NN
    __shared__ int wsum[16];
    __shared__ int woff[16];
    const int tid = threadIdx.x;
    const int lane = tid & 63, wv = tid >> 6;
    const int base = tid * CH;
    int vals[CH];
    int v = 0;
    #pragma unroll
    for (int i = 0; i < CH; i++) {
        int idx = base + i;
        vals[i] = (idx < NN) ? deg[idx] : 0;
        v += vals[i];
    }
    int x = v;
    #pragma unroll
    for (int off = 1; off < 64; off <<= 1) {
        int t = __shfl_up(x, off);
        if (lane >= off) x += t;
    }
    if (lane == 63) wsum[wv] = x;
    __syncthreads();
    if (tid == 0) {
        int run = 0;
        for (int j = 0; j < 16; j++) { woff[j] = run; run += wsum[j]; }
        row_ptr[NN] = run;
    }
    __syncthreads();
    int excl = x - v + woff[wv];
    #pragma unroll
    for (int i = 0; i < CH; i++) {
        int idx = base + i;
        if (idx < NN) row_ptr[idx] = excl;
        excl += vals[i];
    }
}

__global__ void k_initcur(const int* __restrict__ row_ptr, int* __restrict__ cursor) {
    int i = blockIdx.x * blockDim.x + threadIdx.x;
    if (i < NN) cursor[i] = row_ptr[i];
}

__global__ void k_fill(const int* __restrict__ e32, const long long* __restrict__ e64,
                       const int* __restrict__ flag, int* __restrict__ cursor, int* __restrict__ col) {
    int e = blockIdx.x * blockDim.x + threadIdx.x;
    if (e >= NE) return;
    int is64 = *flag;
    int src = ld_edge(e32, e64, is64, e);
    int dst = ld_edge(e32, e64, is64, (long long)NE + e);
    int pos = atomicAdd(&cursor[dst], 1);
    col[pos] = src;
}

// ---------------- fused GEMM + attention-logit epilogue ----------------
// A[M,K] @ W[K,NOUT] -> Hout[M,NOUT] (f32 or bf16); as_out/ad_out [M,HEADS]
template <int K, int NOUT, int HEADS, int OUT_BF16>
__global__ __launch_bounds__(256) void k_gemm_att(
    const float* __restrict__ A, const float* __restrict__ W,
    const float* __restrict__ atts, const float* __restrict__ attd,
    void* __restrict__ HoutV, float* __restrict__ as_out, float* __restrict__ ad_out, int M)
{
    constexpr int BM = 64, BK = 32;
    constexpr int TN = NOUT / 16;
    constexpr int C = NOUT / HEADS;
    __shared__ float As[BM][BK + 4];
    __shared__ float Bs[BK][NOUT];
    __shared__ float red_s[BM * HEADS];
    __shared__ float red_d[BM * HEADS];
    const int tid = threadIdx.x;
    const int tc = tid & 15, tr = tid >> 4;
    const int row0 = blockIdx.x * BM;

    float acc[4][TN];
    #pragma unroll
    for (int r = 0; r < 4; r++)
        #pragma unroll
        for (int j = 0; j < TN; j++) acc[r][j] = 0.f;

    for (int kc = 0; kc < K; kc += BK) {
        #pragma unroll
        for (int j = 0; j < 2; j++) {
            int idx = tid + j * 256;
            int r = idx >> 3, c4 = (idx & 7) * 4;
            float4 v = make_float4(0.f, 0.f, 0.f, 0.f);
            int gr = row0 + r;
            if (gr < M) v = *(const float4*)(A + (size_t)gr * K + kc + c4);
            *(float4*)&As[r][c4] = v;
        }
        #pragma unroll
        for (int j = 0; j < BK * NOUT / 4 / 256; j++) {
            int idx = tid + j * 256;
            int r = idx / (NOUT / 4), c4 = (idx % (NOUT / 4)) * 4;
            *(float4*)&Bs[r][c4] = *(const float4*)(W + (size_t)(kc + r) * NOUT + c4);
        }
        __syncthreads();
        #pragma unroll
        for (int k = 0; k < BK; k++) {
            float a[4];
            #pragma unroll
            for (int r = 0; r < 4; r++) a[r] = As[tr * 4 + r][k];
            float b[TN];
            #pragma unroll
            for (int j = 0; j < TN; j += 4) *(float4*)&b[j] = *(const float4*)&Bs[k][tc * TN + j];
            #pragma unroll
            for (int r = 0; r < 4; r++)
                #pragma unroll
                for (int j = 0; j < TN; j++) acc[r][j] = fmaf(a[r], b[j], acc[r][j]);
        }
        __syncthreads();
    }

    // write projected features
    #pragma unroll
    for (int r = 0; r < 4; r++) {
        int gr = row0 + tr * 4 + r;
        if (gr < M) {
            if (OUT_BF16) {
                u16* Hout = (u16*)HoutV;
                #pragma unroll
                for (int j = 0; j < TN; j += 4) {
                    ushort4 pk;
                    pk.x = f2bf(acc[r][j + 0]);
                    pk.y = f2bf(acc[r][j + 1]);
                    pk.z = f2bf(acc[r][j + 2]);
                    pk.w = f2bf(acc[r][j + 3]);
                    *(ushort4*)(Hout + (size_t)gr * NOUT + tc * TN + j) = pk;
                }
            } else {
                float* Hout = (float*)HoutV;
                #pragma unroll
                for (int j = 0; j < TN; j += 4)
                    *(float4*)(Hout + (size_t)gr * NOUT + tc * TN + j) = *(float4*)&acc[r][j];
            }
        }
    }

    // attention logit partial dots -> LDS reduce
    for (int idx = tid; idx < BM * HEADS; idx += 256) { red_s[idx] = 0.f; red_d[idx] = 0.f; }
    __syncthreads();
    const int col0 = tc * TN;
    const int head = col0 / C;
    #pragma unroll
    for (int r = 0; r < 4; r++) {
        float ps = 0.f, pd = 0.f;
        #pragma unroll
        for (int j = 0; j < TN; j++) {
            ps = fmaf(acc[r][j], atts[col0 + j], ps);
            pd = fmaf(acc[r][j], attd[col0 + j], pd);
        }
        atomicAdd(&red_s[(tr * 4 + r) * HEADS + head], ps);
        atomicAdd(&red_d[(tr * 4 + r) * HEADS + head], pd);
    }
    __syncthreads();
    for (int idx = tid; idx < BM * HEADS; idx += 256) {
        int r = idx / HEADS;
        int gr = row0 + r;
        if (gr < M) {
            as_out[(size_t)gr * HEADS + (idx % HEADS)] = red_s[idx];
            ad_out[(size_t)gr * HEADS + (idx % HEADS)] = red_d[idx];
        }
    }
}

// ---------------- aggregation layer 1: wave per dst, chunked online softmax, bf16 gather ----------------
__global__ __launch_bounds__(256) void k_agg1(
    const int* __restrict__ row_ptr, const int* __restrict__ col,
    const u16* __restrict__ Hb, const float* __restrict__ as_, const float* __restrict__ ad_,
    const float* __restrict__ bias, float* __restrict__ outp)
{
    int n = blockIdx.x * 4 + (threadIdx.x >> 6);
    if (n >= NN) return;
    const int lane = threadIdx.x & 63;
    const int head = lane >> 4;          // lanes g*16..g*16+15 own head g; channels lane*4..+3
    const int el = lane & 15;
    const int gbase = lane & 48;
    float ad0 = ad_[(size_t)n * H1 + head];
    int beg = row_ptr[n], end = row_ptr[n + 1];
    int cnt = end - beg + 1;             // +1: self loop first
    float m = -1e30f, s = 0.f;
    float4 acc = make_float4(0.f, 0.f, 0.f, 0.f);
    for (int c = 0; c < cnt; c += 16) {
        int idx = c + el;
        int srcl = n;
        float ev = -1e30f;
        if (idx < cnt) {
            srcl = (idx == 0) ? n : col[beg + idx - 1];
            float t = as_[(size_t)srcl * H1 + head] + ad0;
            ev = t > 0.f ? t : 0.2f * t;
        }
        float cm = ev;
        cm = fmaxf(cm, __shfl_xor(cm, 1));
        cm = fmaxf(cm, __shfl_xor(cm, 2));
        cm = fmaxf(cm, __shfl_xor(cm, 4));
        cm = fmaxf(cm, __shfl_xor(cm, 8));
        float nm = fmaxf(m, cm);
        float sc = __expf(m - nm);
        m = nm;
        float p = __expf(ev - nm);       // 0 for invalid lanes
        float ps = p;
        ps += __shfl_xor(ps, 1);
        ps += __shfl_xor(ps, 2);
        ps += __shfl_xor(ps, 4);
        ps += __shfl_xor(ps, 8);
        s = s * sc + ps;
        acc.x *= sc; acc.y *= sc; acc.z *= sc; acc.w *= sc;
        int jmax = min(16, cnt - c);
        for (int j = 0; j < jmax; ++j) {
            int srcj = __shfl(srcl, gbase + j);       // same value across groups -> wave-uniform
            float pj = __shfl(p, gbase + j);          // per-head p
            ushort4 hv = *(const ushort4*)(Hb + (size_t)srcj * HC1 + lane * 4);
            acc.x = fmaf(pj, bf2f(hv.x), acc.x);
            acc.y = fmaf(pj, bf2f(hv.y), acc.y);
            acc.z = fmaf(pj, bf2f(hv.z), acc.z);
            acc.w = fmaf(pj, bf2f(hv.w), acc.w);
        }
    }
    float inv = 1.f / s;
    float4 bv = *(const float4*)(bias + lane * 4);
    float4 o;
    o.x = acc.x * inv + bv.x;
    o.y = acc.y * inv + bv.y;
    o.z = acc.z * inv + bv.z;
    o.w = acc.w * inv + bv.w;
    o.x = o.x > 0.f ? o.x : __expf(o.x) - 1.f;   // ELU
    o.y = o.y > 0.f ? o.y : __expf(o.y) - 1.f;
    o.z = o.z > 0.f ? o.z : __expf(o.z) - 1.f;
    o.w = o.w > 0.f ? o.w : __expf(o.w) - 1.f;
    *(float4*)(outp + (size_t)n * HC1 + lane * 4) = o;
}

// ---------------- aggregation layer 2: wave per dst, chunk-64, f32 gather ----------------
__global__ __launch_bounds__(256) void k_agg2(
    const int* __restrict__ row_ptr, const int* __restrict__ col,
    const float* __restrict__ Hp, const float* __restrict__ as_, const float* __restrict__ ad_,
    const float* __restrict__ bias, float* __restrict__ outp)
{
    int n = blockIdx.x * 4 + (threadIdx.x >> 6);
    if (n >= NN) return;
    const int lane = threadIdx.x & 63;
    float ad0 = ad_[n];
    int beg = row_ptr[n], end = row_ptr[n + 1];
    int cnt = end - beg + 1;
    float m = -1e30f, s = 0.f;
    float2 acc = make_float2(0.f, 0.f);
    for (int c = 0; c < cnt; c += 64) {
        int idx = c + lane;
        int srcl = n;
        float ev = -1e30f;
        if (idx < cnt) {
            srcl = (idx == 0) ? n : col[beg + idx - 1];
            float t = as_[srcl] + ad0;
            ev = t > 0.f ? t : 0.2f * t;
        }
        float cm = ev;
        #pragma unroll
        for (int off = 1; off < 64; off <<= 1) cm = fmaxf(cm, __shfl_xor(cm, off));
        float nm = fmaxf(m, cm);
        float sc = __expf(m - nm);
        m = nm;
        float p = __expf(ev - nm);
        float ps = p;
        #pragma unroll
        for (int off = 1; off < 64; off <<= 1) ps += __shfl_xor(ps, off);
        s = s * sc + ps;
        acc.x *= sc; acc.y *= sc;
        int jmax = min(64, cnt - c);
        for (int j = 0; j < jmax; ++j) {
            int srcj = __shfl(srcl, j);
            float pj = __shfl(p, j);
            float2 hv = *(const float2*)(Hp + (size_t)srcj * HC2 + lane * 2);
            acc.x = fmaf(pj, hv.x, acc.x);
            acc.y = fmaf(pj, hv.y, acc.y);
        }
    }
    float inv = 1.f / s;
    float2 bv = *(const float2*)(bias + lane * 2);
    float2 o = make_float2(acc.x * inv + bv.x, acc.y * inv + bv.y);
    *(float2*)(outp + (size_t)n * HC2 + lane * 2) = o;
}

// ---------------- launch ----------------
extern "C" void kernel_launch(void* const* d_in, const int* in_sizes, int n_in,
                              void* d_out, int out_size, void* d_ws, size_t ws_size,
                              hipStream_t stream) {
    const float* x   = (const float*)d_in[0];
    const int*       e32 = (const int*)d_in[1];
    const long long* e64 = (const long long*)d_in[1];
    const float* W1  = (const float*)d_in[2];
    const float* as1w = (const float*)d_in[3];
    const float* ad1w = (const float*)d_in[4];
    const float* b1  = (const float*)d_in[5];
    const float* W2  = (const float*)d_in[6];
    const float* as2w = (const float*)d_in[7];
    const float* ad2w = (const float*)d_in[8];
    const float* b2  = (const float*)d_in[9];
    float* out = (float*)d_out;

    char* w = (char*)d_ws;
    auto carve = [&](size_t bytes) -> void* {
        void* p = (void*)w;
        w += (bytes + 255) & ~(size_t)255;
        return p;
    };
    int*   flag    = (int*)carve(4);
    int*   row_ptr = (int*)carve((NN + 1) * sizeof(int));
    int*   cursor  = (int*)carve(NN * sizeof(int));
    int*   col     = (int*)carve(NE * sizeof(int));
    float* as1     = (float*)carve((size_t)NN * H1 * sizeof(float));
    float* ad1     = (float*)carve((size_t)NN * H1 * sizeof(float));
    float* as2     = (float*)carve((size_t)NN * sizeof(float));
    float* ad2     = (float*)carve((size_t)NN * sizeof(float));
    u16*   h1b     = (u16*)carve((size_t)NN * HC1 * sizeof(u16));     // bf16 layer-1 features
    float* h2in    = (float*)carve((size_t)NN * HC1 * sizeof(float)); // f32 ELU output -> GEMM2 input
    float* h2      = (float*)carve((size_t)NN * HC2 * sizeof(float)); // f32 layer-2 features

    const int TPB = 256;
    const int gN  = (NN + TPB - 1) / TPB;
    const int gE  = (NE + TPB - 1) / TPB;
    const int gM  = (NN + 63) / 64;
    const int gAgg = (NN + 3) / 4;

    // CSR build
    k_detect<<<1, 64, 0, stream>>>(e32, flag);
    k_zero<<<gN, TPB, 0, stream>>>(cursor, NN);
    k_count<<<gE, TPB, 0, stream>>>(e32, e64, flag, cursor);
    k_scan<<<1, 1024, 0, stream>>>(cursor, row_ptr);
    k_initcur<<<gN, TPB, 0, stream>>>(row_ptr, cursor);
    k_fill<<<gE, TPB, 0, stream>>>(e32, e64, flag, cursor, col);

    // layer 1
    k_gemm_att<F1, HC1, H1, 1><<<gM, TPB, 0, stream>>>(x, W1, as1w, ad1w, (void*)h1b, as1, ad1, NN);
    k_agg1<<<gAgg, TPB, 0, stream>>>(row_ptr, col, h1b, as1, ad1, b1, h2in);

    // layer 2
    k_gemm_att<HC1, HC2, 1, 0><<<gM, TPB, 0, stream>>>(h2in, W2, as2w, ad2w, (void*)h2, as2, ad2, NN);
    k_agg2<<<gAgg, TPB, 0, stream>>>(row_ptr, col, h2, as2, ad2, b2, out);
}

// Round 4
// 333.326 us; speedup vs baseline: 1.6064x; 1.3759x over previous
//
#include <hip/hip_runtime.h>
#include <hip/hip_bf16.h>

#define NN 50000
#define NE 800000

constexpr int H1 = 4, C1 = 64, F1 = 128, HC1 = 256;
constexpr int HC2 = 128;

typedef unsigned short u16;
typedef unsigned int u32;
typedef __attribute__((ext_vector_type(8))) short bf16x8;
typedef __attribute__((ext_vector_type(4))) float f32x4;

__device__ __forceinline__ float bf2f(u16 h) {
    return __uint_as_float(((u32)h) << 16);
}
__device__ __forceinline__ u16 f2bf(float f) {
    u32 u = __float_as_uint(f);
    u32 r = (u + 0x7fffu + ((u >> 16) & 1u)) >> 16;   // RTN-even
    return (u16)r;
}

// ---------------- edge index access (int32 vs int64 hedge) ----------------
__device__ __forceinline__ int ld_edge(const int* e32, const long long* e64, int is64, long long idx) {
    return is64 ? (int)e64[idx] : e32[idx];
}

__global__ void k_detect(const int* __restrict__ e32, int* __restrict__ flag) {
    if (threadIdx.x == 0 && blockIdx.x == 0) {
        int z = 1;
        for (int i = 0; i < 16; i++)
            if (e32[2 * i + 1] != 0) z = 0;   // int64 little-endian high words
        *flag = z;
    }
}

// ---------------- CSR build ----------------
__global__ void k_zero(int* __restrict__ p, int n) {
    int i = blockIdx.x * blockDim.x + threadIdx.x;
    if (i < n) p[i] = 0;
}

__global__ void k_count(const int* __restrict__ e32, const long long* __restrict__ e64,
                        const int* __restrict__ flag, int* __restrict__ deg) {
    int e = blockIdx.x * blockDim.x + threadIdx.x;
    if (e >= NE) return;
    int is64 = *flag;
    int dst = ld_edge(e32, e64, is64, (long long)NE + e);
    atomicAdd(&deg[dst], 1);
}

__global__ __launch_bounds__(1024) void k_scan(const int* __restrict__ deg, int* __restrict__ row_ptr) {
    constexpr int CH = 49;   // 1024*49 = 50176 >= NN
    __shared__ int wsum[16];
    __shared__ int woff[16];
    const int tid = threadIdx.x;
    const int lane = tid & 63, wv = tid >> 6;
    const int base = tid * CH;
    int vals[CH];
    int v = 0;
    #pragma unroll
    for (int i = 0; i < CH; i++) {
        int idx = base + i;
        vals[i] = (idx < NN) ? deg[idx] : 0;
        v += vals[i];
    }
    int x = v;
    #pragma unroll
    for (int off = 1; off < 64; off <<= 1) {
        int t = __shfl_up(x, off);
        if (lane >= off) x += t;
    }
    if (lane == 63) wsum[wv] = x;
    __syncthreads();
    if (tid == 0) {
        int run = 0;
        for (int j = 0; j < 16; j++) { woff[j] = run; run += wsum[j]; }
        row_ptr[NN] = run;
    }
    __syncthreads();
    int excl = x - v + woff[wv];
    #pragma unroll
    for (int i = 0; i < CH; i++) {
        int idx = base + i;
        if (idx < NN) row_ptr[idx] = excl;
        excl += vals[i];
    }
}

__global__ void k_initcur(const int* __restrict__ row_ptr, int* __restrict__ cursor) {
    int i = blockIdx.x * blockDim.x + threadIdx.x;
    if (i < NN) cursor[i] = row_ptr[i];
}

__global__ void k_fill(const int* __restrict__ e32, const long long* __restrict__ e64,
                       const int* __restrict__ flag, int* __restrict__ cursor, int* __restrict__ col) {
    int e = blockIdx.x * blockDim.x + threadIdx.x;
    if (e >= NE) return;
    int is64 = *flag;
    int src = ld_edge(e32, e64, is64, e);
    int dst = ld_edge(e32, e64, is64, (long long)NE + e);
    int pos = atomicAdd(&cursor[dst], 1);
    col[pos] = src;
}

// ---------------- W prep: transpose + bf16 convert.  W[K][N] f32 -> Wt[N][K] bf16 ----------------
__global__ __launch_bounds__(256) void k_prepw(const float* __restrict__ W, u16* __restrict__ Wt,
                                               int K, int N) {
    __shared__ float t[32][33];
    int nt = N >> 5;
    int bx = blockIdx.x % nt, by = blockIdx.x / nt;
    int tx = threadIdx.x & 31, ty = threadIdx.x >> 5;   // ty 0..7
    #pragma unroll
    for (int i = 0; i < 4; i++) {
        int r = by * 32 + ty + i * 8;
        t[ty + i * 8][tx] = W[(size_t)r * N + bx * 32 + tx];
    }
    __syncthreads();
    #pragma unroll
    for (int i = 0; i < 4; i++) {
        int n = bx * 32 + ty + i * 8;
        Wt[(size_t)n * K + by * 32 + tx] = f2bf(t[tx][ty + i * 8]);
    }
}

// ---------------- MFMA GEMM + attention-logit epilogue ----------------
// A[M,K] (f32 or bf16) @ Wt[NOUT,K] (bf16, pre-transposed) -> Hout[M,NOUT] bf16
// plus as_out/ad_out [M,HEADS] f32.
// A_BF16=0 -> TPB must be 256;  A_BF16=1 -> TPB must be 128. WAVES = NOUT/64.
template <int K, int NOUT, int HEADS, int A_BF16, int TPB>
__global__ __launch_bounds__(TPB) void k_gemm_mfma(
    const void* __restrict__ Ain, const u16* __restrict__ Wt,
    const float* __restrict__ atts, const float* __restrict__ attd,
    u16* __restrict__ Hout, float* __restrict__ as_out, float* __restrict__ ad_out, int M)
{
    constexpr int BM = 64, BK = 32;
    constexpr int NK = K / BK;
    constexpr int C = NOUT / HEADS;
    constexpr int LDA = 40;                         // u16 per LDS row (80 B padded)
    __shared__ __align__(16) u16 As[2][BM * LDA];
    __shared__ float red_s[BM * HEADS];
    __shared__ float red_d[BM * HEADS];

    const int tid = threadIdx.x;
    const int w = tid >> 6;
    const int l = tid & 63;
    const int l15 = l & 15, lk = l >> 4;
    const int row0 = blockIdx.x * BM;
    const int col0 = w * 64;

    for (int i = tid; i < BM * HEADS; i += TPB) { red_s[i] = 0.f; red_d[i] = 0.f; }

    f32x4 acc[4][4];
    #pragma unroll
    for (int rt = 0; rt < 4; rt++)
        #pragma unroll
        for (int nt = 0; nt < 4; nt++)
            acc[rt][nt] = (f32x4){0.f, 0.f, 0.f, 0.f};

    auto stage = [&](int kc, int b) {
        if constexpr (A_BF16) {
            const u16* Ab = (const u16*)Ain;      // TPB=128: 2 thr/row, 16 bf16 each
            int r = tid >> 1, c = (tid & 1) * 16;
            int gr = row0 + r;
            bf16x8 v0 = {0,0,0,0,0,0,0,0}, v1 = {0,0,0,0,0,0,0,0};
            if (gr < M) {
                v0 = *(const bf16x8*)(Ab + (size_t)gr * K + kc * BK + c);
                v1 = *(const bf16x8*)(Ab + (size_t)gr * K + kc * BK + c + 8);
            }
            *(bf16x8*)&As[b][r * LDA + c] = v0;
            *(bf16x8*)&As[b][r * LDA + c + 8] = v1;
        } else {
            const float* Af = (const float*)Ain;  // TPB=256: 4 thr/row, 8 f32 each
            int r = tid >> 2, c = (tid & 3) * 8;
            int gr = row0 + r;
            float4 f0 = make_float4(0.f, 0.f, 0.f, 0.f), f1 = f0;
            if (gr < M) {
                f0 = *(const float4*)(Af + (size_t)gr * K + kc * BK + c);
                f1 = *(const float4*)(Af + (size_t)gr * K + kc * BK + c + 4);
            }
            bf16x8 v;
            v[0] = (short)f2bf(f0.x); v[1] = (short)f2bf(f0.y);
            v[2] = (short)f2bf(f0.z); v[3] = (short)f2bf(f0.w);
            v[4] = (short)f2bf(f1.x); v[5] = (short)f2bf(f1.y);
            v[6] = (short)f2bf(f1.z); v[7] = (short)f2bf(f1.w);
            *(bf16x8*)&As[b][r * LDA + c] = v;
        }
    };

    stage(0, 0);
    for (int kc = 0; kc < NK; ++kc) {
        __syncthreads();
        // A fragments from LDS (row = rt*16 + l15, k-chunk = lk*8)
        bf16x8 afr[4];
        #pragma unroll
        for (int rt = 0; rt < 4; rt++)
            afr[rt] = *(const bf16x8*)&As[kc & 1][(rt * 16 + l15) * LDA + lk * 8];
        // B fragments straight from L2 (col = col0+nt*16+l15, k-chunk = lk*8)
        bf16x8 bfr[4];
        #pragma unroll
        for (int nt = 0; nt < 4; nt++)
            bfr[nt] = *(const bf16x8*)(Wt + (size_t)(col0 + nt * 16 + l15) * K + kc * BK + lk * 8);
        if (kc + 1 < NK) stage(kc + 1, (kc + 1) & 1);
        #pragma unroll
        for (int rt = 0; rt < 4; rt++)
            #pragma unroll
            for (int nt = 0; nt < 4; nt++)
                acc[rt][nt] = __builtin_amdgcn_mfma_f32_16x16x32_bf16(afr[rt], bfr[nt], acc[rt][nt], 0, 0, 0);
    }

    // ---- write H (bf16): D layout col=l&15, row=(l>>4)*4+t  [m89-verified] ----
    #pragma unroll
    for (int rt = 0; rt < 4; rt++) {
        #pragma unroll
        for (int t = 0; t < 4; t++) {
            int gr = row0 + rt * 16 + lk * 4 + t;
            if (gr < M) {
                #pragma unroll
                for (int nt = 0; nt < 4; nt++)
                    Hout[(size_t)gr * NOUT + col0 + nt * 16 + l15] = f2bf(acc[rt][nt][t]);
            }
        }
    }

    // ---- attention logits: per-row dot with att vectors, reduce over 16-lane col group ----
    float avs[4], avd[4];
    #pragma unroll
    for (int nt = 0; nt < 4; nt++) {
        int gc = col0 + nt * 16 + l15;          // flattened [H,C] index == global col
        avs[nt] = atts[gc];
        avd[nt] = attd[gc];
    }
    const int headw = col0 / C;
    #pragma unroll
    for (int rt = 0; rt < 4; rt++) {
        #pragma unroll
        for (int t = 0; t < 4; t++) {
            float ps = 0.f, pd = 0.f;
            #pragma unroll
            for (int nt = 0; nt < 4; nt++) {
                ps = fmaf(acc[rt][nt][t], avs[nt], ps);
                pd = fmaf(acc[rt][nt][t], avd[nt], pd);
            }
            ps += __shfl_xor(ps, 1); ps += __shfl_xor(ps, 2);
            ps += __shfl_xor(ps, 4); ps += __shfl_xor(ps, 8);
            pd += __shfl_xor(pd, 1); pd += __shfl_xor(pd, 2);
            pd += __shfl_xor(pd, 4); pd += __shfl_xor(pd, 8);
            if (l15 == 0) {
                int row = rt * 16 + lk * 4 + t;
                atomicAdd(&red_s[row * HEADS + headw], ps);
                atomicAdd(&red_d[row * HEADS + headw], pd);
            }
        }
    }
    __syncthreads();
    for (int i = tid; i < BM * HEADS; i += TPB) {
        int gr = row0 + i / HEADS;
        if (gr < M) {
            as_out[(size_t)gr * HEADS + i % HEADS] = red_s[i];
            ad_out[(size_t)gr * HEADS + i % HEADS] = red_d[i];
        }
    }
}

// ---------------- aggregation layer 1: wave per dst, chunked online softmax, bf16 gather ----------------
// output: bf16 (feeds GEMM2 as A)
__global__ __launch_bounds__(256) void k_agg1(
    const int* __restrict__ row_ptr, const int* __restrict__ col,
    const u16* __restrict__ Hb, const float* __restrict__ as_, const float* __restrict__ ad_,
    const float* __restrict__ bias, u16* __restrict__ outp)
{
    int n = blockIdx.x * 4 + (threadIdx.x >> 6);
    if (n >= NN) return;
    const int lane = threadIdx.x & 63;
    const int head = lane >> 4;
    const int el = lane & 15;
    const int gbase = lane & 48;
    float ad0 = ad_[(size_t)n * H1 + head];
    int beg = row_ptr[n], end = row_ptr[n + 1];
    int cnt = end - beg + 1;             // +1: self loop first
    float m = -1e30f, s = 0.f;
    float4 acc = make_float4(0.f, 0.f, 0.f, 0.f);
    for (int c = 0; c < cnt; c += 16) {
        int idx = c + el;
        int srcl = n;
        float ev = -1e30f;
        if (idx < cnt) {
            srcl = (idx == 0) ? n : col[beg + idx - 1];
            float t = as_[(size_t)srcl * H1 + head] + ad0;
            ev = t > 0.f ? t : 0.2f * t;
        }
        float cm = ev;
        cm = fmaxf(cm, __shfl_xor(cm, 1));
        cm = fmaxf(cm, __shfl_xor(cm, 2));
        cm = fmaxf(cm, __shfl_xor(cm, 4));
        cm = fmaxf(cm, __shfl_xor(cm, 8));
        float nm = fmaxf(m, cm);
        float sc = __expf(m - nm);
        m = nm;
        float p = __expf(ev - nm);
        float ps = p;
        ps += __shfl_xor(ps, 1);
        ps += __shfl_xor(ps, 2);
        ps += __shfl_xor(ps, 4);
        ps += __shfl_xor(ps, 8);
        s = s * sc + ps;
        acc.x *= sc; acc.y *= sc; acc.z *= sc; acc.w *= sc;
        int jmax = min(16, cnt - c);
        for (int j = 0; j < jmax; ++j) {
            int srcj = __shfl(srcl, gbase + j);
            float pj = __shfl(p, gbase + j);
            ushort4 hv = *(const ushort4*)(Hb + (size_t)srcj * HC1 + lane * 4);
            acc.x = fmaf(pj, bf2f(hv.x), acc.x);
            acc.y = fmaf(pj, bf2f(hv.y), acc.y);
            acc.z = fmaf(pj, bf2f(hv.z), acc.z);
            acc.w = fmaf(pj, bf2f(hv.w), acc.w);
        }
    }
    float inv = 1.f / s;
    float4 bv = *(const float4*)(bias + lane * 4);
    float4 o;
    o.x = acc.x * inv + bv.x;
    o.y = acc.y * inv + bv.y;
    o.z = acc.z * inv + bv.z;
    o.w = acc.w * inv + bv.w;
    o.x = o.x > 0.f ? o.x : __expf(o.x) - 1.f;   // ELU
    o.y = o.y > 0.f ? o.y : __expf(o.y) - 1.f;
    o.z = o.z > 0.f ? o.z : __expf(o.z) - 1.f;
    o.w = o.w > 0.f ? o.w : __expf(o.w) - 1.f;
    ushort4 ob;
    ob.x = f2bf(o.x); ob.y = f2bf(o.y); ob.z = f2bf(o.z); ob.w = f2bf(o.w);
    *(ushort4*)(outp + (size_t)n * HC1 + lane * 4) = ob;
}

// ---------------- aggregation layer 2: wave per dst, chunk-64, bf16 gather ----------------
__global__ __launch_bounds__(256) void k_agg2(
    const int* __restrict__ row_ptr, const int* __restrict__ col,
    const u16* __restrict__ Hb, const float* __restrict__ as_, const float* __restrict__ ad_,
    const float* __restrict__ bias, float* __restrict__ outp)
{
    int n = blockIdx.x * 4 + (threadIdx.x >> 6);
    if (n >= NN) return;
    const int lane = threadIdx.x & 63;
    float ad0 = ad_[n];
    int beg = row_ptr[n], end = row_ptr[n + 1];
    int cnt = end - beg + 1;
    float m = -1e30f, s = 0.f;
    float2 acc = make_float2(0.f, 0.f);
    for (int c = 0; c < cnt; c += 64) {
        int idx = c + lane;
        int srcl = n;
        float ev = -1e30f;
        if (idx < cnt) {
            srcl = (idx == 0) ? n : col[beg + idx - 1];
            float t = as_[srcl] + ad0;
            ev = t > 0.f ? t : 0.2f * t;
        }
        float cm = ev;
        #pragma unroll
        for (int off = 1; off < 64; off <<= 1) cm = fmaxf(cm, __shfl_xor(cm, off));
        float nm = fmaxf(m, cm);
        float sc = __expf(m - nm);
        m = nm;
        float p = __expf(ev - nm);
        float ps = p;
        #pragma unroll
        for (int off = 1; off < 64; off <<= 1) ps += __shfl_xor(ps, off);
        s = s * sc + ps;
        acc.x *= sc; acc.y *= sc;
        int jmax = min(64, cnt - c);
        for (int j = 0; j < jmax; ++j) {
            int srcj = __shfl(srcl, j);
            float pj = __shfl(p, j);
            ushort2 hv = *(const ushort2*)(Hb + (size_t)srcj * HC2 + lane * 2);
            acc.x = fmaf(pj, bf2f(hv.x), acc.x);
            acc.y = fmaf(pj, bf2f(hv.y), acc.y);
        }
    }
    float inv = 1.f / s;
    float2 bv = *(const float2*)(bias + lane * 2);
    float2 o = make_float2(acc.x * inv + bv.x, acc.y * inv + bv.y);
    *(float2*)(outp + (size_t)n * HC2 + lane * 2) = o;
}

// ---------------- launch ----------------
extern "C" void kernel_launch(void* const* d_in, const int* in_sizes, int n_in,
                              void* d_out, int out_size, void* d_ws, size_t ws_size,
                              hipStream_t stream) {
    const float* x   = (const float*)d_in[0];
    const int*       e32 = (const int*)d_in[1];
    const long long* e64 = (const long long*)d_in[1];
    const float* W1  = (const float*)d_in[2];
    const float* as1w = (const float*)d_in[3];
    const float* ad1w = (const float*)d_in[4];
    const float* b1  = (const float*)d_in[5];
    const float* W2  = (const float*)d_in[6];
    const float* as2w = (const float*)d_in[7];
    const float* ad2w = (const float*)d_in[8];
    const float* b2  = (const float*)d_in[9];
    float* out = (float*)d_out;

    char* w = (char*)d_ws;
    auto carve = [&](size_t bytes) -> void* {
        void* p = (void*)w;
        w += (bytes + 255) & ~(size_t)255;
        return p;
    };
    int*   flag    = (int*)carve(4);
    int*   row_ptr = (int*)carve((NN + 1) * sizeof(int));
    int*   cursor  = (int*)carve(NN * sizeof(int));
    int*   col     = (int*)carve(NE * sizeof(int));
    float* as1     = (float*)carve((size_t)NN * H1 * sizeof(float));
    float* ad1     = (float*)carve((size_t)NN * H1 * sizeof(float));
    float* as2     = (float*)carve((size_t)NN * sizeof(float));
    float* ad2     = (float*)carve((size_t)NN * sizeof(float));
    u16*   h1b     = (u16*)carve((size_t)NN * HC1 * sizeof(u16));     // bf16 layer-1 features
    u16*   h2in    = (u16*)carve((size_t)NN * HC1 * sizeof(u16));     // bf16 ELU output -> GEMM2 A
    u16*   h2b     = (u16*)carve((size_t)NN * HC2 * sizeof(u16));     // bf16 layer-2 features
    u16*   wt1     = (u16*)carve((size_t)F1 * HC1 * sizeof(u16));     // Wt1 [256][128] bf16
    u16*   wt2     = (u16*)carve((size_t)HC1 * HC2 * sizeof(u16));    // Wt2 [128][256] bf16

    const int TPB = 256;
    const int gN  = (NN + TPB - 1) / TPB;
    const int gE  = (NE + TPB - 1) / TPB;
    const int gM  = (NN + 63) / 64;        // 782
    const int gAgg = (NN + 3) / 4;

    // W prep (independent of CSR)
    k_prepw<<<(F1 / 32) * (HC1 / 32), 256, 0, stream>>>(W1, wt1, F1, HC1);
    k_prepw<<<(HC1 / 32) * (HC2 / 32), 256, 0, stream>>>(W2, wt2, HC1, HC2);

    // CSR build
    k_detect<<<1, 64, 0, stream>>>(e32, flag);
    k_zero<<<gN, TPB, 0, stream>>>(cursor, NN);
    k_count<<<gE, TPB, 0, stream>>>(e32, e64, flag, cursor);
    k_scan<<<1, 1024, 0, stream>>>(cursor, row_ptr);
    k_initcur<<<gN, TPB, 0, stream>>>(row_ptr, cursor);
    k_fill<<<gE, TPB, 0, stream>>>(e32, e64, flag, cursor, col);

    // layer 1: x f32 @ Wt1 -> h1b bf16, logits
    k_gemm_mfma<F1, HC1, H1, 0, 256><<<gM, 256, 0, stream>>>(
        (const void*)x, wt1, as1w, ad1w, h1b, as1, ad1, NN);
    k_agg1<<<gAgg, TPB, 0, stream>>>(row_ptr, col, h1b, as1, ad1, b1, h2in);

    // layer 2: h2in bf16 @ Wt2 -> h2b bf16, logits
    k_gemm_mfma<HC1, HC2, 1, 1, 128><<<gM, 128, 0, stream>>>(
        (const void*)h2in, wt2, as2w, ad2w, h2b, as2, ad2, NN);
    k_agg2<<<gAgg, TPB, 0, stream>>>(row_ptr, col, h2b, as2, ad2, b2, out);
}